// Round 7
// baseline (343.195 us; speedup 1.0000x reference)
//
#include <hip/hip_runtime.h>
#include <hip/hip_bf16.h>
#include <hip/hip_fp16.h>

// GCN 2-layer: out = Ahat * relu(Ahat*(X W1)+b1) * W2 + b2
// Round 20: structural cuts. Aggs/gemm64 inner loops = R17 (proven best).
//  - build: direct scatter. memset(deg) -> deg_hist (global atomicAdd into
//    n counters, L2-resident) -> rowscan (per-bucket pad8 scan -> row_ptr/
//    rend/dinv/cursor + pad fill) -> scatter (cursor atomicAdd, csr[p]=src).
//    Eliminates bedges write+read (12.8 MB) and two LDS-atomic passes.
//  - agg64+gemm32h FUSED: per 128 dst rows, gather+relu -> LDS fp16
//    AsT[k][row] (stride 140 halves: 8B-aligned half4 reads, bank-spread
//    writes) -> barrier -> W2 GEMM -> xs2. Eliminates th (25.6 MB round
//    trip + 1 dispatch). Bitwise-identical numerics (same fp16 rounding
//    point, same FMA order).
//  - agg32, gemm64: R17 verbatim.

#define N_FEAT_IN 64
#define B2SHIFT 9        // 512 dst nodes per coarse bucket
#define CHUNK 4096       // edges per block in edge-sweep kernels
#define CSRCAP 16384     // csr bucket region capacity (edges + pad8, 8-aligned)

struct alignas(8) half4 { __half2 lo, hi; };
struct alignas(16) half8 { __half2 h[4]; };

// ---- deg_hist: per-dst degree via global atomics (deg pre-zeroed) ----
__global__ __launch_bounds__(1024) void deg_hist(const int* __restrict__ dst,
                                                 int* __restrict__ deg, int E) {
    int base = blockIdx.x * CHUNK;
    int end = min(base + CHUNK, E);
    for (int i = base + threadIdx.x; i < end; i += 1024)
        atomicAdd(&deg[dst[i]], 1);
}

// ---- rowscan: per-bucket pad8 scan -> row_ptr/rend/dinv/cursor + pad fill ----
__global__ __launch_bounds__(512) void rowscan_k(const int* __restrict__ deg,
                                                 int* __restrict__ row_ptr,
                                                 int* __restrict__ rend,
                                                 int* __restrict__ cursor,
                                                 float* __restrict__ dinv,
                                                 int* __restrict__ csr_src, int n) {
    __shared__ int lh[512];
    int t = threadIdx.x;
    int b = blockIdx.x;
    int d = (b << B2SHIFT) + t;
    int c = (d < n) ? deg[d] : 0;
    int cp = (c + 7) & ~7;               // padded degree (8-aligned)
    lh[t] = cp;
    __syncthreads();
    for (int off = 1; off < 512; off <<= 1) {
        int a = (t >= off) ? lh[t - off] : 0;
        __syncthreads();
        lh[t] += a;
        __syncthreads();
    }
    if (d < n) {
        int rbeg = b * CSRCAP + lh[t] - cp;   // 8-aligned exclusive offset
        row_ptr[d] = rbeg;
        rend[d] = rbeg + cp;
        cursor[d] = rbeg;
        dinv[d] = rsqrtf((float)c + 1.0f);
        for (int i = c; i < cp; ++i) csr_src[rbeg + i] = n;  // pad -> zero row
    }
}

// ---- scatter: place src ids via per-row global cursors ----
__global__ __launch_bounds__(1024) void scatter_k(const int* __restrict__ src,
                                                  const int* __restrict__ dst,
                                                  int* __restrict__ cursor,
                                                  int* __restrict__ csr_src, int E) {
    int base = blockIdx.x * CHUNK;
    int end = min(base + CHUNK, E);
    for (int i = base + threadIdx.x; i < end; i += 1024) {
        int p = atomicAdd(&cursor[dst[i]], 1);
        csr_src[p] = src[i];
    }
}

// ---- gemm64: xs1[n+1][64] fp16 = half( dinv[row] * (X W1) ) ----
__global__ __launch_bounds__(256) void gemm64(const float* __restrict__ A,
                                              const float* __restrict__ W,
                                              const float* __restrict__ dinv,
                                              __half* __restrict__ outh, int n) {
    __shared__ float AsT[64][132];   // [k][row]
    __shared__ float Ws[64][64];

    const int t = threadIdx.x;
    const int r0 = blockIdx.x * 128;

    if (blockIdx.x == 0 && t < 64)   // zero pad row n
        outh[(size_t)n * 64 + t] = __float2half(0.f);

    for (int i = t; i < 64 * 16; i += 256) {
        int k = i >> 4;
        int c4 = (i & 15) * 4;
        *(float4*)&Ws[k][c4] = *(const float4*)&W[k * 64 + c4];
    }
    for (int i = t; i < 128 * 16; i += 256) {
        int row = i >> 4;
        int c4 = (i & 15) * 4;
        int g = r0 + row;
        float4 v = make_float4(0.f, 0.f, 0.f, 0.f);
        if (g < n) v = *(const float4*)&A[(size_t)g * 64 + c4];
        AsT[c4 + 0][row] = v.x;
        AsT[c4 + 1][row] = v.y;
        AsT[c4 + 2][row] = v.z;
        AsT[c4 + 3][row] = v.w;
    }
    __syncthreads();

    const int rg = t >> 3;
    const int cg = t & 7;
    float acc[4][8];
#pragma unroll
    for (int r = 0; r < 4; ++r)
#pragma unroll
        for (int j = 0; j < 8; ++j) acc[r][j] = 0.f;

#pragma unroll 4
    for (int k = 0; k < 64; ++k) {
        float4 a = *(const float4*)&AsT[k][rg * 4];
        float4 w0 = *(const float4*)&Ws[k][cg * 8];
        float4 w1 = *(const float4*)&Ws[k][cg * 8 + 4];
        float av[4] = {a.x, a.y, a.z, a.w};
        float wv[8] = {w0.x, w0.y, w0.z, w0.w, w1.x, w1.y, w1.z, w1.w};
#pragma unroll
        for (int r = 0; r < 4; ++r)
#pragma unroll
            for (int j = 0; j < 8; ++j)
                acc[r][j] = fmaf(av[r], wv[j], acc[r][j]);
    }

#pragma unroll
    for (int r = 0; r < 4; ++r) {
        int g = r0 + rg * 4 + r;
        if (g < n) {
            float sc = dinv[g];
            half8 h;
            h.h[0] = __floats2half2_rn(acc[r][0] * sc, acc[r][1] * sc);
            h.h[1] = __floats2half2_rn(acc[r][2] * sc, acc[r][3] * sc);
            h.h[2] = __floats2half2_rn(acc[r][4] * sc, acc[r][5] * sc);
            h.h[3] = __floats2half2_rn(acc[r][6] * sc, acc[r][7] * sc);
            *(half8*)&outh[(size_t)g * 64 + cg * 8] = h;
        }
    }
}

#define ACC8(v)                                                       \
    {                                                                 \
        float2 f0 = __half22float2((v).h[0]);                         \
        float2 f1 = __half22float2((v).h[1]);                         \
        float2 f2 = __half22float2((v).h[2]);                         \
        float2 f3 = __half22float2((v).h[3]);                         \
        a0 += f0.x; a1 += f0.y; a2 += f1.x; a3 += f1.y;               \
        a4 += f2.x; a5 += f2.y; a6 += f3.x; a7 += f3.y;               \
    }

#define AGG_LOOP8(STRIDE)                                             \
    if (beg < end) {                                                  \
        int4 ia = *(const int4*)&csr_src[beg];                        \
        int4 ib = *(const int4*)&csr_src[beg + 4];                    \
        int jb = beg;                                                 \
        for (;;) {                                                    \
            int jn = jb + 8;                                          \
            bool more = jn < end;                                     \
            int js = more ? jn : beg;                                 \
            int4 na = *(const int4*)&csr_src[js];                     \
            int4 nb = *(const int4*)&csr_src[js + 4];                 \
            half8 v0 = xrow[(size_t)ia.x * STRIDE];                   \
            half8 v1 = xrow[(size_t)ia.y * STRIDE];                   \
            half8 v2 = xrow[(size_t)ia.z * STRIDE];                   \
            half8 v3 = xrow[(size_t)ia.w * STRIDE];                   \
            half8 v4 = xrow[(size_t)ib.x * STRIDE];                   \
            half8 v5 = xrow[(size_t)ib.y * STRIDE];                   \
            half8 v6 = xrow[(size_t)ib.z * STRIDE];                   \
            half8 v7 = xrow[(size_t)ib.w * STRIDE];                   \
            ACC8(v0); ACC8(v1); ACC8(v2); ACC8(v3);                   \
            ACC8(v4); ACC8(v5); ACC8(v6); ACC8(v7);                   \
            if (!more) break;                                         \
            jb = jn; ia = na; ib = nb;                                \
        }                                                             \
    }

// ---- fused agg64 + gemm32h: 128 dst rows/block ----
// Phase A: 4 sub-batches of 32 rows, 8 lanes/row, gather+relu -> AsT fp16.
// Phase B: xs2[g] = half( dinv[g] * (AsT^T W2) ), thread tile 2 rows x 8 cols.
__global__ __launch_bounds__(256) void agg_gemm32(const int* __restrict__ row_ptr,
                                                  const int* __restrict__ rend,
                                                  const int* __restrict__ csr_src,
                                                  const float* __restrict__ dinv,
                                                  const __half* __restrict__ xs1,
                                                  const float* __restrict__ b1,
                                                  const float* __restrict__ W2,
                                                  __half* __restrict__ xs2, int n) {
    __shared__ __half AsT[64][140];   // [k][row], stride 280B (16B-aligned rows)
    __shared__ float Ws[64][32];

    const int t = threadIdx.x;
    const int r0 = blockIdx.x * 128;

    if (blockIdx.x == 0 && t < 32)    // zero pad row n of xs2
        xs2[(size_t)n * 32 + t] = __float2half(0.f);

    for (int i = t; i < 64 * 8; i += 256) {
        int k = i >> 3;
        int c4 = (i & 7) * 4;
        *(float4*)&Ws[k][c4] = *(const float4*)&W2[k * 32 + c4];
    }

    // Phase A: aggregate 128 rows (4 subs x 32 rows), 8 lanes/row, half8/lane
    const int sr = t >> 3;            // 0..31 row-in-sub
    const int c = t & 7;              // feat slice 8c..8c+7
    const half8* __restrict__ xrow = (const half8*)xs1 + c;
    float4 ba = *(const float4*)&b1[8 * c];
    float4 bb = *(const float4*)&b1[8 * c + 4];

#pragma unroll
    for (int sub = 0; sub < 4; ++sub) {
        int row = sub * 32 + sr;
        int d = r0 + row;
        if (d < n) {
            half8 sv = xrow[(size_t)d * 8];    // self-loop
            float a0, a1, a2, a3, a4, a5, a6, a7;
            {
                float2 f0 = __half22float2(sv.h[0]), f1 = __half22float2(sv.h[1]);
                float2 f2 = __half22float2(sv.h[2]), f3 = __half22float2(sv.h[3]);
                a0 = f0.x; a1 = f0.y; a2 = f1.x; a3 = f1.y;
                a4 = f2.x; a5 = f2.y; a6 = f3.x; a7 = f3.y;
            }
            int beg = row_ptr[d];
            int end = rend[d];
            AGG_LOOP8(8)
            float di = dinv[d];
            AsT[8 * c + 0][row] = __float2half(fmaxf(fmaf(di, a0, ba.x), 0.f));
            AsT[8 * c + 1][row] = __float2half(fmaxf(fmaf(di, a1, ba.y), 0.f));
            AsT[8 * c + 2][row] = __float2half(fmaxf(fmaf(di, a2, ba.z), 0.f));
            AsT[8 * c + 3][row] = __float2half(fmaxf(fmaf(di, a3, ba.w), 0.f));
            AsT[8 * c + 4][row] = __float2half(fmaxf(fmaf(di, a4, bb.x), 0.f));
            AsT[8 * c + 5][row] = __float2half(fmaxf(fmaf(di, a5, bb.y), 0.f));
            AsT[8 * c + 6][row] = __float2half(fmaxf(fmaf(di, a6, bb.z), 0.f));
            AsT[8 * c + 7][row] = __float2half(fmaxf(fmaf(di, a7, bb.w), 0.f));
        }
    }
    __syncthreads();

    // Phase B: GEMM, thread tile 2 rows x 8 cols
    const int rg = t >> 2;            // 0..63 -> rows rg*2..+1
    const int cg = t & 3;             // 0..3  -> cols cg*8..+7
    float acc[2][8];
#pragma unroll
    for (int r = 0; r < 2; ++r)
#pragma unroll
        for (int j = 0; j < 8; ++j) acc[r][j] = 0.f;

#pragma unroll 4
    for (int k = 0; k < 64; ++k) {
        float2 af = __half22float2(*(const __half2*)&AsT[k][rg * 2]);
        float4 w0 = *(const float4*)&Ws[k][cg * 8];
        float4 w1 = *(const float4*)&Ws[k][cg * 8 + 4];
        float av[2] = {af.x, af.y};
        float wv[8] = {w0.x, w0.y, w0.z, w0.w, w1.x, w1.y, w1.z, w1.w};
#pragma unroll
        for (int r = 0; r < 2; ++r)
#pragma unroll
            for (int j = 0; j < 8; ++j)
                acc[r][j] = fmaf(av[r], wv[j], acc[r][j]);
    }

#pragma unroll
    for (int r = 0; r < 2; ++r) {
        int g = r0 + rg * 2 + r;
        if (g < n) {
            float sc = dinv[g];
            half8 h;
            h.h[0] = __floats2half2_rn(acc[r][0] * sc, acc[r][1] * sc);
            h.h[1] = __floats2half2_rn(acc[r][2] * sc, acc[r][3] * sc);
            h.h[2] = __floats2half2_rn(acc[r][4] * sc, acc[r][5] * sc);
            h.h[3] = __floats2half2_rn(acc[r][6] * sc, acc[r][7] * sc);
            *(half8*)&xs2[(size_t)g * 32 + cg * 8] = h;
        }
    }
}

// ---- agg32: 16 rows/wave, 4 lanes/row, half8/lane; out = dinv*acc + b2 ----
__global__ __launch_bounds__(256) void agg32(const int* __restrict__ row_ptr,
                                             const int* __restrict__ rend,
                                             const int* __restrict__ csr_src,
                                             const float* __restrict__ dinv,
                                             const __half* __restrict__ xs2,
                                             const float* __restrict__ b2,
                                             float* __restrict__ out, int n) {
    int d = blockIdx.x * 64 + (threadIdx.x >> 2);  // 64 rows/block
    if (d >= n) return;
    int c = threadIdx.x & 3;                       // half8 slice (feats 8c..8c+7)
    const half8* __restrict__ xrow = (const half8*)xs2 + c;  // row stride 4 half8

    half8 sv = xrow[(size_t)d * 4];                // self-loop
    float a0, a1, a2, a3, a4, a5, a6, a7;
    {
        float2 f0 = __half22float2(sv.h[0]), f1 = __half22float2(sv.h[1]);
        float2 f2 = __half22float2(sv.h[2]), f3 = __half22float2(sv.h[3]);
        a0 = f0.x; a1 = f0.y; a2 = f1.x; a3 = f1.y;
        a4 = f2.x; a5 = f2.y; a6 = f3.x; a7 = f3.y;
    }

    int beg = row_ptr[d];
    int end = rend[d];
    AGG_LOOP8(4)

    float di = dinv[d];
    float4 ba = *(const float4*)&b2[8 * c];
    float4 bb = *(const float4*)&b2[8 * c + 4];
    float4 r0, r1;
    r0.x = fmaf(di, a0, ba.x);
    r0.y = fmaf(di, a1, ba.y);
    r0.z = fmaf(di, a2, ba.z);
    r0.w = fmaf(di, a3, ba.w);
    r1.x = fmaf(di, a4, bb.x);
    r1.y = fmaf(di, a5, bb.y);
    r1.z = fmaf(di, a6, bb.z);
    r1.w = fmaf(di, a7, bb.w);
    *(float4*)&out[(size_t)d * 32 + 8 * c] = r0;
    *(float4*)&out[(size_t)d * 32 + 8 * c + 4] = r1;
}

extern "C" void kernel_launch(void* const* d_in, const int* in_sizes, int n_in,
                              void* d_out, int out_size, void* d_ws, size_t ws_size,
                              hipStream_t stream) {
    const float* x  = (const float*)d_in[0];   // [n, 64]
    const int*   ei = (const int*)d_in[1];     // [2, E]
    const float* W1 = (const float*)d_in[2];   // [64, 64]
    const float* b1 = (const float*)d_in[3];   // [64]
    const float* W2 = (const float*)d_in[4];   // [64, 32]
    const float* b2 = (const float*)d_in[5];   // [32]
    float* out = (float*)d_out;                // [n, 32]

    const int n = in_sizes[0] / N_FEAT_IN;     // 100000
    const int E = in_sizes[1] / 2;             // 1600000
    const int* srcI = ei;
    const int* dstI = ei + E;

    const int NB = (n + 511) >> B2SHIFT;       // 196 coarse buckets
    const int NR = (E + CHUNK - 1) / CHUNK;    // 391 chunks

    // workspace layout (256B aligned)
    char* ws = (char*)d_ws;
    size_t off = 0;
    auto alloc = [&](size_t bytes) {
        void* p = ws + off;
        off += (bytes + 255) & ~(size_t)255;
        return p;
    };
    float*    dinv    = (float*)alloc((size_t)n * 4);
    int*      row_ptr = (int*)alloc((size_t)n * 4);
    int*      rend    = (int*)alloc((size_t)n * 4);
    int*      deg     = (int*)alloc((size_t)n * 4);
    int*      cursor  = (int*)alloc((size_t)n * 4);
    int*      csr_src = (int*)alloc((size_t)NB * CSRCAP * 4);       // 12.8MB
    __half*   xs1     = (__half*)alloc((size_t)(n + 1) * 64 * 2);   // +pad row
    __half*   xs2     = (__half*)alloc((size_t)(n + 1) * 32 * 2);   // +pad row

    // 1) build: zero degrees -> histogram -> per-bucket scan -> direct scatter
    hipMemsetAsync(deg, 0, (size_t)n * 4, stream);
    deg_hist<<<NR, 1024, 0, stream>>>(dstI, deg, E);
    rowscan_k<<<NB, 512, 0, stream>>>(deg, row_ptr, rend, cursor, dinv, csr_src, n);
    scatter_k<<<NR, 1024, 0, stream>>>(srcI, dstI, cursor, csr_src, E);

    // 2) layer 1 GEMM: xs1 = half(dinv .* (X W1))
    gemm64<<<(n + 127) / 128, 256, 0, stream>>>(x, W1, dinv, xs1, n);

    // 3) fused layer-1 aggregate + layer-2 transform -> xs2
    agg_gemm32<<<(n + 127) / 128, 256, 0, stream>>>(row_ptr, rend, csr_src, dinv,
                                                    xs1, b1, W2, xs2, n);

    // 4) layer-2 aggregate -> out
    agg32<<<(n + 63) / 64, 256, 0, stream>>>(row_ptr, rend, csr_src, dinv, xs2, b2, out, n);
}

// Round 8
// 198.829 us; speedup vs baseline: 1.7261x; 1.7261x over previous
//
#include <hip/hip_runtime.h>
#include <hip/hip_bf16.h>
#include <hip/hip_fp16.h>

// GCN 2-layer: out = Ahat * relu(Ahat*(X W1)+b1) * W2 + b2
// Round 21: REVERT to R17 (best measured: 198.3us). R20's direct-scatter
// build (124us scatter_k: random-store RFO + cursor contention) and
// agg+gemm fusion (+15us: serialized sub-batches) both regressed.
// Configuration: atomic-base 3-dispatch build + register-tiled GEMMs +
// 8-edge-batch padded-CSR aggs. Aggregation phase is at the measured
// random-gather ceiling (~39G lines/s ≈ 2.4 TB/s effective; invariant
// under instr count, MLP depth, vector width, and two locality schemes).

#define N_FEAT_IN 64
#define B2SHIFT 9        // 512 dst nodes per coarse bucket
#define CHUNK 4096       // edges per block in place
#define CAP 12288        // bedges bucket region capacity (mean 8163 + 45 sigma)
#define CSRCAP 16384     // csr_src bucket region capacity (CAP + 512*7 pad, 8-al)

struct alignas(8) half4 { __half2 lo, hi; };
struct alignas(16) half8 { __half2 h[4]; };

// ---- init: zero the global bucket cursors ----
__global__ __launch_bounds__(256) void init_k(int* __restrict__ gcur) {
    gcur[threadIdx.x] = 0;
}

// ---- place: per-chunk LDS hist -> global atomic base -> scatter ----
__global__ __launch_bounds__(1024) void place_k(const int* __restrict__ src,
                                                const int* __restrict__ dst,
                                                int* __restrict__ gcur,
                                                unsigned* __restrict__ bedges, int E) {
    __shared__ int h[256];
    __shared__ int cur[256];
    int t = threadIdx.x;
    if (t < 256) h[t] = 0;
    __syncthreads();
    int base = blockIdx.x * CHUNK;
    int end = min(base + CHUNK, E);
    for (int i = base + t; i < end; i += 1024)
        atomicAdd(&h[dst[i] >> B2SHIFT], 1);
    __syncthreads();
    if (t < 256) {
        int cnt = h[t];
        int b0 = cnt ? atomicAdd(&gcur[t], cnt) : 0;  // device-scope
        cur[t] = t * CAP + b0;
    }
    __syncthreads();
    for (int i = base + t; i < end; i += 1024) {
        int d = dst[i];
        int p = atomicAdd(&cur[d >> B2SHIFT], 1);     // LDS atomic
        bedges[p] = ((unsigned)src[i] << B2SHIFT) | (unsigned)(d & 511);
    }
}

// ---- bucket_csr: hist -> padded scan -> row_ptr/rend/dinv -> scatter ----
__global__ __launch_bounds__(1024) void bucket_csr(const int* __restrict__ gcnt,
                                                   const unsigned* __restrict__ bedges,
                                                   int* __restrict__ row_ptr,
                                                   int* __restrict__ rend,
                                                   float* __restrict__ dinv,
                                                   int* __restrict__ csr_src, int n) {
    __shared__ int lh[512];
    __shared__ int cur[512];
    int t = threadIdx.x;
    if (t < 512) lh[t] = 0;
    __syncthreads();
    int b = blockIdx.x;
    int beg = b * CAP;
    int end = beg + gcnt[b];
    for (int i = beg + t; i < end; i += 1024)
        atomicAdd(&lh[bedges[i] & 511], 1);
    __syncthreads();
    int c = (t < 512) ? lh[t] : 0;       // true degree (no self-loop)
    __syncthreads();
    int cp = (c + 7) & ~7;               // padded degree
    if (t < 512) lh[t] = cp;
    __syncthreads();
    for (int off = 1; off < 512; off <<= 1) {
        int a = (t < 512 && t >= off) ? lh[t - off] : 0;
        __syncthreads();
        if (t < 512) lh[t] += a;
        __syncthreads();
    }
    int pb = b * CSRCAP;                 // 8-aligned bucket csr base
    if (t < 512) {
        int d = (b << B2SHIFT) + t;
        int rbeg = pb + lh[t] - cp;      // 8-aligned exclusive padded offset
        cur[t] = rbeg;
        if (d < n) {
            row_ptr[d] = rbeg;
            rend[d] = rbeg + cp;
            dinv[d] = rsqrtf((float)c + 1.0f);
            for (int i = c; i < cp; ++i) csr_src[rbeg + i] = n;  // pad -> zero row
        }
    }
    __syncthreads();
    for (int i = beg + t; i < end; i += 1024) {
        unsigned v = bedges[i];
        int p = atomicAdd(&cur[v & 511], 1);  // LDS atomic
        csr_src[p] = (int)(v >> B2SHIFT);
    }
}

// ---- gemm64: xs1[n+1][64] fp16 = half( dinv[row] * (X W1) ) ----
// 128 rows/block, thread tile 4 rows x 8 cols, A transposed in LDS.
__global__ __launch_bounds__(256) void gemm64(const float* __restrict__ A,
                                              const float* __restrict__ W,
                                              const float* __restrict__ dinv,
                                              __half* __restrict__ outh, int n) {
    __shared__ float AsT[64][132];   // [k][row], stride 528B (16B aligned)
    __shared__ float Ws[64][64];

    const int t = threadIdx.x;
    const int r0 = blockIdx.x * 128;

    if (blockIdx.x == 0 && t < 64)   // zero pad row n
        outh[(size_t)n * 64 + t] = __float2half(0.f);

    for (int i = t; i < 64 * 16; i += 256) {
        int k = i >> 4;
        int c4 = (i & 15) * 4;
        *(float4*)&Ws[k][c4] = *(const float4*)&W[k * 64 + c4];
    }
    for (int i = t; i < 128 * 16; i += 256) {
        int row = i >> 4;
        int c4 = (i & 15) * 4;
        int g = r0 + row;
        float4 v = make_float4(0.f, 0.f, 0.f, 0.f);
        if (g < n) v = *(const float4*)&A[(size_t)g * 64 + c4];
        AsT[c4 + 0][row] = v.x;
        AsT[c4 + 1][row] = v.y;
        AsT[c4 + 2][row] = v.z;
        AsT[c4 + 3][row] = v.w;
    }
    __syncthreads();

    const int rg = t >> 3;           // 0..31 -> rows rg*4..+3
    const int cg = t & 7;            // 0..7  -> cols cg*8..+7
    float acc[4][8];
#pragma unroll
    for (int r = 0; r < 4; ++r)
#pragma unroll
        for (int j = 0; j < 8; ++j) acc[r][j] = 0.f;

#pragma unroll 4
    for (int k = 0; k < 64; ++k) {
        float4 a = *(const float4*)&AsT[k][rg * 4];
        float4 w0 = *(const float4*)&Ws[k][cg * 8];
        float4 w1 = *(const float4*)&Ws[k][cg * 8 + 4];
        float av[4] = {a.x, a.y, a.z, a.w};
        float wv[8] = {w0.x, w0.y, w0.z, w0.w, w1.x, w1.y, w1.z, w1.w};
#pragma unroll
        for (int r = 0; r < 4; ++r)
#pragma unroll
            for (int j = 0; j < 8; ++j)
                acc[r][j] = fmaf(av[r], wv[j], acc[r][j]);
    }

#pragma unroll
    for (int r = 0; r < 4; ++r) {
        int g = r0 + rg * 4 + r;
        if (g < n) {
            float sc = dinv[g];
            half8 h;
            h.h[0] = __floats2half2_rn(acc[r][0] * sc, acc[r][1] * sc);
            h.h[1] = __floats2half2_rn(acc[r][2] * sc, acc[r][3] * sc);
            h.h[2] = __floats2half2_rn(acc[r][4] * sc, acc[r][5] * sc);
            h.h[3] = __floats2half2_rn(acc[r][6] * sc, acc[r][7] * sc);
            *(half8*)&outh[(size_t)g * 64 + cg * 8] = h;
        }
    }
}

#define ACC8(v)                                                       \
    {                                                                 \
        float2 f0 = __half22float2((v).h[0]);                         \
        float2 f1 = __half22float2((v).h[1]);                         \
        float2 f2 = __half22float2((v).h[2]);                         \
        float2 f3 = __half22float2((v).h[3]);                         \
        a0 += f0.x; a1 += f0.y; a2 += f1.x; a3 += f1.y;               \
        a4 += f2.x; a5 += f2.y; a6 += f3.x; a7 += f3.y;               \
    }

// ---- agg64: 8 rows/wave, 8 lanes/row, half8/lane; t = relu(dinv*acc+b1) ----
__global__ __launch_bounds__(256) void agg64(const int* __restrict__ row_ptr,
                                             const int* __restrict__ rend,
                                             const int* __restrict__ csr_src,
                                             const float* __restrict__ dinv,
                                             const __half* __restrict__ xs1,
                                             const float* __restrict__ b1,
                                             __half* __restrict__ th, int n) {
    int d = blockIdx.x * 32 + (threadIdx.x >> 3);  // 32 rows/block
    if (d >= n) return;
    int c = threadIdx.x & 7;                       // half8 slice (feats 8c..8c+7)
    const half8* __restrict__ xrow = (const half8*)xs1 + c;  // row stride 8 half8

    half8 sv = xrow[(size_t)d * 8];                // self-loop
    float a0, a1, a2, a3, a4, a5, a6, a7;
    {
        float2 f0 = __half22float2(sv.h[0]), f1 = __half22float2(sv.h[1]);
        float2 f2 = __half22float2(sv.h[2]), f3 = __half22float2(sv.h[3]);
        a0 = f0.x; a1 = f0.y; a2 = f1.x; a3 = f1.y;
        a4 = f2.x; a5 = f2.y; a6 = f3.x; a7 = f3.y;
    }

    int beg = row_ptr[d];
    int end = rend[d];
    if (beg < end) {
        int4 ia = *(const int4*)&csr_src[beg];
        int4 ib = *(const int4*)&csr_src[beg + 4];
        int jb = beg;
        for (;;) {
            int jn = jb + 8;
            bool more = jn < end;
            int js = more ? jn : beg;              // prefetch next batch
            int4 na = *(const int4*)&csr_src[js];
            int4 nb = *(const int4*)&csr_src[js + 4];
            half8 v0 = xrow[(size_t)ia.x * 8];
            half8 v1 = xrow[(size_t)ia.y * 8];
            half8 v2 = xrow[(size_t)ia.z * 8];
            half8 v3 = xrow[(size_t)ia.w * 8];
            half8 v4 = xrow[(size_t)ib.x * 8];
            half8 v5 = xrow[(size_t)ib.y * 8];
            half8 v6 = xrow[(size_t)ib.z * 8];
            half8 v7 = xrow[(size_t)ib.w * 8];
            ACC8(v0); ACC8(v1); ACC8(v2); ACC8(v3);
            ACC8(v4); ACC8(v5); ACC8(v6); ACC8(v7);
            if (!more) break;
            jb = jn; ia = na; ib = nb;
        }
    }

    float di = dinv[d];
    float4 ba = *(const float4*)&b1[8 * c];
    float4 bb = *(const float4*)&b1[8 * c + 4];
    float t0 = fmaxf(fmaf(di, a0, ba.x), 0.f);
    float t1 = fmaxf(fmaf(di, a1, ba.y), 0.f);
    float t2 = fmaxf(fmaf(di, a2, ba.z), 0.f);
    float t3 = fmaxf(fmaf(di, a3, ba.w), 0.f);
    float t4 = fmaxf(fmaf(di, a4, bb.x), 0.f);
    float t5 = fmaxf(fmaf(di, a5, bb.y), 0.f);
    float t6 = fmaxf(fmaf(di, a6, bb.z), 0.f);
    float t7 = fmaxf(fmaf(di, a7, bb.w), 0.f);
    half8 o;
    o.h[0] = __floats2half2_rn(t0, t1);
    o.h[1] = __floats2half2_rn(t2, t3);
    o.h[2] = __floats2half2_rn(t4, t5);
    o.h[3] = __floats2half2_rn(t6, t7);
    *(half8*)&th[(size_t)d * 64 + 8 * c] = o;
}

// ---- gemm32h: xs2[n+1][32] fp16 = half( dinv[row] * (t W2) ) ----
// 256 rows/block, thread tile 4 rows x 8 cols, A transposed in LDS.
__global__ __launch_bounds__(256) void gemm32h(const __half* __restrict__ Ah,
                                               const float* __restrict__ W,
                                               const float* __restrict__ dinv,
                                               __half* __restrict__ outh, int n) {
    __shared__ float AsT[64][260];   // [k][row], stride 1040B (16B aligned)
    __shared__ float Ws[64][32];

    const int t = threadIdx.x;
    const int r0 = blockIdx.x * 256;

    if (blockIdx.x == 0 && t < 32)   // zero pad row n
        outh[(size_t)n * 32 + t] = __float2half(0.f);

    for (int i = t; i < 64 * 8; i += 256) {
        int k = i >> 3;
        int c4 = (i & 7) * 4;
        *(float4*)&Ws[k][c4] = *(const float4*)&W[k * 32 + c4];
    }
    for (int i = t; i < 256 * 8; i += 256) {
        int row = i >> 3;
        int c8 = (i & 7) * 8;
        int g = r0 + row;
        if (g < n) {
            half8 hv = *(const half8*)&Ah[(size_t)g * 64 + c8];
            float2 f0 = __half22float2(hv.h[0]), f1 = __half22float2(hv.h[1]);
            float2 f2 = __half22float2(hv.h[2]), f3 = __half22float2(hv.h[3]);
            AsT[c8 + 0][row] = f0.x; AsT[c8 + 1][row] = f0.y;
            AsT[c8 + 2][row] = f1.x; AsT[c8 + 3][row] = f1.y;
            AsT[c8 + 4][row] = f2.x; AsT[c8 + 5][row] = f2.y;
            AsT[c8 + 6][row] = f3.x; AsT[c8 + 7][row] = f3.y;
        } else {
#pragma unroll
            for (int j = 0; j < 8; ++j) AsT[c8 + j][row] = 0.f;
        }
    }
    __syncthreads();

    const int rg = t >> 2;           // 0..63 -> rows rg*4..+3
    const int cg = t & 3;            // 0..3  -> cols cg*8..+7
    float acc[4][8];
#pragma unroll
    for (int r = 0; r < 4; ++r)
#pragma unroll
        for (int j = 0; j < 8; ++j) acc[r][j] = 0.f;

#pragma unroll 4
    for (int k = 0; k < 64; ++k) {
        float4 a = *(const float4*)&AsT[k][rg * 4];
        float4 w0 = *(const float4*)&Ws[k][cg * 8];
        float4 w1 = *(const float4*)&Ws[k][cg * 8 + 4];
        float av[4] = {a.x, a.y, a.z, a.w};
        float wv[8] = {w0.x, w0.y, w0.z, w0.w, w1.x, w1.y, w1.z, w1.w};
#pragma unroll
        for (int r = 0; r < 4; ++r)
#pragma unroll
            for (int j = 0; j < 8; ++j)
                acc[r][j] = fmaf(av[r], wv[j], acc[r][j]);
    }

#pragma unroll
    for (int r = 0; r < 4; ++r) {
        int g = r0 + rg * 4 + r;
        if (g < n) {
            float sc = dinv[g];
            half8 h;
            h.h[0] = __floats2half2_rn(acc[r][0] * sc, acc[r][1] * sc);
            h.h[1] = __floats2half2_rn(acc[r][2] * sc, acc[r][3] * sc);
            h.h[2] = __floats2half2_rn(acc[r][4] * sc, acc[r][5] * sc);
            h.h[3] = __floats2half2_rn(acc[r][6] * sc, acc[r][7] * sc);
            *(half8*)&outh[(size_t)g * 32 + cg * 8] = h;
        }
    }
}

// ---- agg32: 16 rows/wave, 4 lanes/row, half8/lane; out = dinv*acc + b2 ----
__global__ __launch_bounds__(256) void agg32(const int* __restrict__ row_ptr,
                                             const int* __restrict__ rend,
                                             const int* __restrict__ csr_src,
                                             const float* __restrict__ dinv,
                                             const __half* __restrict__ xs2,
                                             const float* __restrict__ b2,
                                             float* __restrict__ out, int n) {
    int d = blockIdx.x * 64 + (threadIdx.x >> 2);  // 64 rows/block
    if (d >= n) return;
    int c = threadIdx.x & 3;                       // half8 slice (feats 8c..8c+7)
    const half8* __restrict__ xrow = (const half8*)xs2 + c;  // row stride 4 half8

    half8 sv = xrow[(size_t)d * 4];                // self-loop
    float a0, a1, a2, a3, a4, a5, a6, a7;
    {
        float2 f0 = __half22float2(sv.h[0]), f1 = __half22float2(sv.h[1]);
        float2 f2 = __half22float2(sv.h[2]), f3 = __half22float2(sv.h[3]);
        a0 = f0.x; a1 = f0.y; a2 = f1.x; a3 = f1.y;
        a4 = f2.x; a5 = f2.y; a6 = f3.x; a7 = f3.y;
    }

    int beg = row_ptr[d];
    int end = rend[d];
    if (beg < end) {
        int4 ia = *(const int4*)&csr_src[beg];
        int4 ib = *(const int4*)&csr_src[beg + 4];
        int jb = beg;
        for (;;) {
            int jn = jb + 8;
            bool more = jn < end;
            int js = more ? jn : beg;
            int4 na = *(const int4*)&csr_src[js];
            int4 nb = *(const int4*)&csr_src[js + 4];
            half8 v0 = xrow[(size_t)ia.x * 4];
            half8 v1 = xrow[(size_t)ia.y * 4];
            half8 v2 = xrow[(size_t)ia.z * 4];
            half8 v3 = xrow[(size_t)ia.w * 4];
            half8 v4 = xrow[(size_t)ib.x * 4];
            half8 v5 = xrow[(size_t)ib.y * 4];
            half8 v6 = xrow[(size_t)ib.z * 4];
            half8 v7 = xrow[(size_t)ib.w * 4];
            ACC8(v0); ACC8(v1); ACC8(v2); ACC8(v3);
            ACC8(v4); ACC8(v5); ACC8(v6); ACC8(v7);
            if (!more) break;
            jb = jn; ia = na; ib = nb;
        }
    }

    float di = dinv[d];
    float4 ba = *(const float4*)&b2[8 * c];
    float4 bb = *(const float4*)&b2[8 * c + 4];
    float4 r0, r1;
    r0.x = fmaf(di, a0, ba.x);
    r0.y = fmaf(di, a1, ba.y);
    r0.z = fmaf(di, a2, ba.z);
    r0.w = fmaf(di, a3, ba.w);
    r1.x = fmaf(di, a4, bb.x);
    r1.y = fmaf(di, a5, bb.y);
    r1.z = fmaf(di, a6, bb.z);
    r1.w = fmaf(di, a7, bb.w);
    *(float4*)&out[(size_t)d * 32 + 8 * c] = r0;
    *(float4*)&out[(size_t)d * 32 + 8 * c + 4] = r1;
}

extern "C" void kernel_launch(void* const* d_in, const int* in_sizes, int n_in,
                              void* d_out, int out_size, void* d_ws, size_t ws_size,
                              hipStream_t stream) {
    const float* x  = (const float*)d_in[0];   // [n, 64]
    const int*   ei = (const int*)d_in[1];     // [2, E]
    const float* W1 = (const float*)d_in[2];   // [64, 64]
    const float* b1 = (const float*)d_in[3];   // [64]
    const float* W2 = (const float*)d_in[4];   // [64, 32]
    const float* b2 = (const float*)d_in[5];   // [32]
    float* out = (float*)d_out;                // [n, 32]

    const int n = in_sizes[0] / N_FEAT_IN;     // 100000
    const int E = in_sizes[1] / 2;             // 1600000
    const int* srcI = ei;
    const int* dstI = ei + E;

    const int NB = (n + 511) >> B2SHIFT;       // 196 coarse buckets
    const int NR = (E + CHUNK - 1) / CHUNK;    // 391 chunks

    // workspace layout (256B aligned)
    char* ws = (char*)d_ws;
    size_t off = 0;
    auto alloc = [&](size_t bytes) {
        void* p = ws + off;
        off += (bytes + 255) & ~(size_t)255;
        return p;
    };
    float*    dinv    = (float*)alloc((size_t)n * 4);
    int*      row_ptr = (int*)alloc((size_t)(n + 1) * 4);
    int*      rend    = (int*)alloc((size_t)n * 4);
    int*      gcur    = (int*)alloc((size_t)256 * 4);
    unsigned* bedges  = (unsigned*)alloc((size_t)NB * CAP * 4);     // 9.6MB
    int*      csr_src = (int*)alloc((size_t)NB * CSRCAP * 4);       // 12.8MB
    __half*   xs1     = (__half*)alloc((size_t)(n + 1) * 64 * 2);   // +pad row
    __half*   th      = (__half*)alloc((size_t)n * 64 * 2);
    __half*   xs2     = (__half*)alloc((size_t)(n + 1) * 32 * 2);   // +pad row

    // 1) build: init cursors -> place into CAP-strided buckets -> CSR
    init_k<<<1, 256, 0, stream>>>(gcur);
    place_k<<<NR, 1024, 0, stream>>>(srcI, dstI, gcur, bedges, E);
    bucket_csr<<<NB, 1024, 0, stream>>>(gcur, bedges, row_ptr, rend, dinv, csr_src, n);

    // 2) layer 1 GEMM: xs1 = half(dinv .* (X W1))
    gemm64<<<(n + 127) / 128, 256, 0, stream>>>(x, W1, dinv, xs1, n);

    // 3) layer-1 aggregate: t = relu(dinv*(gather+self) + b1)
    agg64<<<(n + 31) / 32, 256, 0, stream>>>(row_ptr, rend, csr_src, dinv, xs1, b1, th, n);

    // 4) layer-2 transform: xs2 = half(dinv .* (t W2))
    gemm32h<<<(n + 255) / 256, 256, 0, stream>>>(th, W2, dinv, xs2, n);

    // 5) layer-2 aggregate -> out
    agg32<<<(n + 63) / 64, 256, 0, stream>>>(row_ptr, rend, csr_src, dinv, xs2, b2, out, n);
}